// Round 6
// baseline (578.499 us; speedup 1.0000x reference)
//
#include <hip/hip_runtime.h>
#include <stdint.h>

typedef unsigned short u16;
typedef __attribute__((ext_vector_type(8))) short s8v;    // 8 x bf16
typedef __attribute__((ext_vector_type(4))) float f4v;    // 4 x f32
typedef __fp16 h2v __attribute__((ext_vector_type(2)));   // 2 x f16
typedef __fp16 h8v __attribute__((ext_vector_type(8)));   // 8 x f16

__device__ __forceinline__ float bu2f(u16 u) {
  return __uint_as_float(((uint32_t)u) << 16);
}
__device__ __forceinline__ u16 f2bu(float f) {
  uint32_t u = __float_as_uint(f);
  u += 0x7fffu + ((u >> 16) & 1u);  // RNE
  return (u16)(u >> 16);
}

union U32H2 { uint32_t u; h2v h; };

__device__ __forceinline__ uint32_t pk2h(float a, float b) {
  U32H2 x;
  x.h = __builtin_amdgcn_cvt_pkrtz(a, b);  // exact for bf16-valued inputs
  return x.u;
}

// ---- input dtype abstraction ----------------------------------------------
template <bool F32> struct In;
template <> struct In<true> {
  static __device__ __forceinline__ float ld(const void* p, long i) {
    return ((const float*)p)[i];
  }
};
template <> struct In<false> {
  static __device__ __forceinline__ float ld(const void* p, long i) {
    return bu2f(((const u16*)p)[i]);
  }
};

// ---- dtype detector (proven) ----------------------------------------------
__global__ void k_detect(const u16* __restrict__ x, int* __restrict__ flag) {
  __shared__ int s[64];
  int cnt = 0;
  for (int i = threadIdx.x; i < 2048; i += 64) {
    int e = (x[i] >> 7) & 0xFF;
    cnt += (e >= 96 && e <= 134) ? 1 : 0;
  }
  s[threadIdx.x] = cnt;
  __syncthreads();
  if (threadIdx.x == 0) {
    int t = 0;
    for (int i = 0; i < 64; ++i) t += s[i];
    *flag = (t >= 1843) ? 0 : 1;  // 0 = bf16, 1 = f32
  }
}

// ---------------------------------------------------------------------------
// Weight transforms into ws:
//  fc1t [128][416] bf16, fc2t [96][128] bf16, w1t [2][2048][96] bf16,
//  w2t [2][96][2048] bf16,
//  cdw: MFMA conv weights: cd1m[3][64][8] f16, cd2m[6][64][8] f16,
//       cb1[6] f32 @dword 2304, cb2[16] f32 @dword 2310. Total 2326 dwords.
// Tap order for conv MFMA (row-padded to 6): t = quad*8 + j,
//   ky = t/6, kxp = t%6; weight 0 for kxp==5 or t>=30 (and n>=6 for conv1).
// ---------------------------------------------------------------------------
__device__ __forceinline__ u16 f2h16(float f) {
  __fp16 h = (__fp16)f;
  u16 r;
  __builtin_memcpy(&r, &h, 2);
  return r;
}

template <bool INF32>
__global__ __launch_bounds__(256) void k_trans(
    const int* __restrict__ flag,
    const void* __restrict__ fc1w, const void* __restrict__ fc2w,
    const void* __restrict__ ew1, const void* __restrict__ ew2,
    const void* __restrict__ c1w, const void* __restrict__ c1b,
    const void* __restrict__ c2w, const void* __restrict__ c2b,
    u16* __restrict__ fc1t, u16* __restrict__ fc2t,
    u16* __restrict__ w1t, u16* __restrict__ w2t,
    uint32_t* __restrict__ cdw) {
  if (*flag != (INF32 ? 1 : 0)) return;
  long gid = (long)blockIdx.x * 256 + threadIdx.x;
  if (gid < 53248) {                       // fc1t: [128 n][416 k]
    int n = (int)(gid / 416), k = (int)(gid % 416);
    fc1t[gid] = (n < 120 && k < 400) ? f2bu(In<INF32>::ld(fc1w, (long)k * 120 + n)) : (u16)0;
  } else if (gid < 65536) {                // fc2t: [96 n][128 k]
    long i = gid - 53248;
    int n = (int)(i / 128), k = (int)(i % 128);
    fc2t[i] = (n < 84 && k < 120) ? f2bu(In<INF32>::ld(fc2w, (long)k * 84 + n)) : (u16)0;
  } else if (gid < 458752) {               // w1t: [2][2048 n][96 k]
    long i = gid - 65536;
    int e = (int)(i / 196608);
    long r = i % 196608;
    int n = (int)(r / 96), k = (int)(r % 96);
    w1t[i] = (k < 84) ? f2bu(In<INF32>::ld(ew1, ((long)e * 84 + k) * 2048 + n)) : (u16)0;
  } else if (gid < 851968) {               // w2t: [2][96 n][2048 k]
    long i = gid - 458752;
    int e = (int)(i / 196608);
    long r = i % 196608;
    int n = (int)(r / 2048), k = (int)(r % 2048);
    w2t[i] = (n < 84) ? f2bu(In<INF32>::ld(ew2, ((long)e * 2048 + k) * 84 + n)) : (u16)0;
  } else if (gid < 856598) {               // conv MFMA weights + biases
    long i = gid - 851968;
    u16* cdh = (u16*)cdw;
    if (i < 1536) {          // cd1m [3 ic][64 lane][8 j]
      int ic = (int)(i >> 9);
      int r = (int)(i & 511);
      int lnn = r >> 3, j = r & 7;
      int n = lnn & 15, qd = lnn >> 4;
      int t = qd * 8 + j, ky = t / 6, kxp = t - ky * 6;
      float v = (n < 6 && t < 30 && kxp < 5)
          ? In<INF32>::ld(c1w, ((long)(n * 3 + ic) * 5 + ky) * 5 + kxp) : 0.f;
      cdh[i] = f2h16(v);
    } else if (i < 4608) {   // cd2m [6 ic][64 lane][8 j]
      long jj = i - 1536;
      int ic = (int)(jj >> 9);
      int r = (int)(jj & 511);
      int lnn = r >> 3, j = r & 7;
      int n = lnn & 15, qd = lnn >> 4;
      int t = qd * 8 + j, ky = t / 6, kxp = t - ky * 6;
      float v = (t < 30 && kxp < 5)
          ? In<INF32>::ld(c2w, ((long)(n * 6 + ic) * 5 + ky) * 5 + kxp) : 0.f;
      cdh[1536 + jj] = f2h16(v);
    } else if (i < 4614) {   // cb1 (f32)
      ((float*)(cdw + 2304))[i - 4608] = In<INF32>::ld(c1b, i - 4608);
    } else if (i < 4630) {   // cb2 (f32)
      ((float*)(cdw + 2310))[i - 4614] = In<INF32>::ld(c2b, i - 4614);
    }
  }
}

// ---------------------------------------------------------------------------
// Conv kernel v5: MFMA implicit-GEMM (unchanged from R5 this round).
// ---------------------------------------------------------------------------
#define CIMG 2
#define XSTR 34           // sx row stride (elems)
#define PSTR 18           // sp1 row stride (elems)
template <bool INF32>
__global__ __launch_bounds__(256) void k_conv(
    const int* __restrict__ flag,
    const void* __restrict__ x,
    const uint32_t* __restrict__ cdw,
    u16* __restrict__ p2, int Btot) {
  if (*flag != (INF32 ? 1 : 0)) return;
  __shared__ __align__(16) u16 sxn[CIMG * 3 * 32 * XSTR];
  __shared__ __align__(16) u16 sxs[CIMG * 3 * 32 * XSTR];
  __shared__ __align__(16) u16 sp1n[CIMG * 6 * 14 * PSTR];
  __shared__ __align__(16) u16 sp1s[CIMG * 6 * 14 * PSTR];
  __shared__ u16 lut1[196];
  __shared__ u16 lut2[32];
  const u16* cdh = (const u16*)cdw;
  const float* cb1f = (const float*)(cdw + 2304);
  const float* cb2f = (const float*)(cdw + 2310);
  const int tid = threadIdx.x;
  const int wv = tid >> 6, ln = tid & 63;
  const int mrow = ln & 15, quad = ln >> 4;
  const long gimg0 = (long)blockIdx.x * CIMG;

  if (tid < 196) {
    int py = tid / 14, px = tid - py * 14;
    lut1[tid] = (u16)((2 * py) * XSTR + 2 * px);
  } else if (tid < 228) {
    int i = tid - 196;
    if (i < 25) {
      int py = i / 5, px = i - py * 5;
      lut2[i] = (u16)((2 * py) * PSTR + 2 * px);
    }
  }
  for (int r = tid; r < CIMG * 6 * 14; r += 256)
    *(uint32_t*)(sp1s + (size_t)r * PSTR + 12) = 0;

  for (int i = tid; i < CIMG * 96; i += 256) {
    int img = i / 96;
    if (gimg0 + img >= Btot) continue;
    int rem = i - img * 96;
    long goff = (gimg0 + img) * 3072 + (long)rem * 32;
    uint32_t e[17];
    if (!INF32) {
      const uint32_t* src = (const uint32_t*)((const u16*)x + goff);
#pragma unroll
      for (int j = 0; j < 16; ++j) {
        uint32_t d = src[j];
        e[j] = pk2h(__uint_as_float(d << 16), __uint_as_float(d & 0xffff0000u));
      }
    } else {
      const float* src = (const float*)x + goff;
#pragma unroll
      for (int j = 0; j < 16; ++j) e[j] = pk2h(src[2 * j], src[2 * j + 1]);
    }
    e[16] = 0;
    uint32_t* dn = (uint32_t*)(sxn + (size_t)i * XSTR);
    uint32_t* dsh = (uint32_t*)(sxs + (size_t)i * XSTR);
#pragma unroll
    for (int j = 0; j < 16; ++j) {
      dn[j] = e[j];
      dsh[j] = (e[j] >> 16) | (e[j + 1] << 16);
    }
  }

  h8v b1[3];
#pragma unroll
  for (int ic = 0; ic < 3; ++ic)
    b1[ic] = *(const h8v*)(cdh + ((size_t)ic * 64 + ln) * 8);
  const float bias1 = (mrow < 6) ? cb1f[mrow] : 0.f;
  int toff1[4];
#pragma unroll
  for (int p = 0; p < 4; ++p) {
    int t = quad * 8 + 2 * p;
    if (t >= 30) t = 24;
    toff1[p] = (t / 6) * (XSTR - 6) + t;
  }
  const int qA = mrow >> 2, dyA = (mrow >> 1) & 1, dxA = mrow & 1;

  __syncthreads();

  const u16* c1base = dxA ? sxs : sxn;
  for (int tg = wv; tg < CIMG * 49; tg += 4) {
    int img = tg / 49, tau = tg - img * 49;
    int pqA = tau * 4 + qA;
    const u16* rb0 = c1base + (size_t)img * (3 * 32 * XSTR) + lut1[pqA] + dyA * XSTR;
    f4v acc = {0.f, 0.f, 0.f, 0.f};
#pragma unroll
    for (int ic = 0; ic < 3; ++ic) {
      const u16* rb = rb0 + ic * (32 * XSTR);
      union { uint32_t w[4]; h8v v; } au;
#pragma unroll
      for (int p = 0; p < 4; ++p)
        au.w[p] = *(const uint32_t*)(rb + toff1[p]);
      acc = __builtin_amdgcn_mfma_f32_16x16x32_f16(au.v, b1[ic], acc, 0, 0, 0);
    }
    float v = fmaxf(fmaxf(acc[0], acc[1]), fmaxf(acc[2], acc[3])) + bias1;
    v = fmaxf(v, 0.f);
    if (mrow < 6) {
      int pqC = tau * 4 + quad;
      int py = (pqC * 4682) >> 16, px = pqC - py * 14;
      int rbase = ((img * 6 + mrow) * 14 + py) * PSTR;
      u16 hv = f2h16(v);
      sp1n[rbase + px] = hv;
      sp1s[rbase + (px ? px - 1 : PSTR - 1)] = hv;
    }
  }

  h8v b2[6];
#pragma unroll
  for (int ic = 0; ic < 6; ++ic)
    b2[ic] = *(const h8v*)(cdh + 1536 + ((size_t)ic * 64 + ln) * 8);
  const float bias2 = cb2f[mrow];
  int toff2[4];
#pragma unroll
  for (int p = 0; p < 4; ++p) {
    int t = quad * 8 + 2 * p;
    if (t >= 30) t = 24;
    toff2[p] = (t / 6) * (PSTR - 6) + t;
  }

  __syncthreads();

  const int NP2 = CIMG * 25;
  const u16* c2base = dxA ? sp1s : sp1n;
  for (int t2 = wv; t2 * 4 < NP2; t2 += 4) {
    int PA = t2 * 4 + qA;
    if (PA >= NP2) PA = NP2 - 1;
    int img = (PA * 41) >> 10, pq = PA - img * 25;
    const u16* rb0 = c2base + (size_t)img * (6 * 14 * PSTR) + lut2[pq] + dyA * PSTR;
    f4v acc = {0.f, 0.f, 0.f, 0.f};
#pragma unroll
    for (int ic = 0; ic < 6; ++ic) {
      const u16* rb = rb0 + ic * (14 * PSTR);
      union { uint32_t w[4]; h8v v; } au;
#pragma unroll
      for (int p = 0; p < 4; ++p)
        au.w[p] = *(const uint32_t*)(rb + toff2[p]);
      acc = __builtin_amdgcn_mfma_f32_16x16x32_f16(au.v, b2[ic], acc, 0, 0, 0);
    }
    float v = fmaxf(fmaxf(acc[0], acc[1]), fmaxf(acc[2], acc[3])) + bias2;
    v = fmaxf(v, 0.f);
    int PC = t2 * 4 + quad;
    if (PC < NP2) {
      int imgc = (PC * 41) >> 10, pqc = PC - imgc * 25;
      if (gimg0 + imgc < Btot)
        p2[(gimg0 + imgc) * 416 + mrow * 25 + pqc] = f2bu(v);
    }
  }

  for (int i = tid; i < CIMG * 16; i += 256) {
    int img = i / 16;
    if (gimg0 + img < Btot) p2[(gimg0 + img) * 416 + 400 + (i & 15)] = 0;
  }
}

// ---------------------------------------------------------------------------
// fcA: fc1 -> fc2 -> gate. 64 tokens/block (unchanged this round).
// ---------------------------------------------------------------------------
template <bool INF32>
__global__ __launch_bounds__(256) void k_fcA(
    const int* __restrict__ flag,
    const u16* __restrict__ p2,
    const u16* __restrict__ fc1t, const u16* __restrict__ fc2t,
    const void* __restrict__ fc1b, const void* __restrict__ fc2b,
    const void* __restrict__ gw,
    u16* __restrict__ a2buf, float* __restrict__ scbuf) {
  if (*flag != (INF32 ? 1 : 0)) return;
  __shared__ __align__(16) char smem[62976];
  u16* a2s = (u16*)smem;                    // [64][104]
  u16* hs = (u16*)(smem + 13312);           // [64][136]
  u16* wbuf = (u16*)(smem + 31232);
  u16* xs = (u16*)(smem + 57856);           // [64][40]

  const int tid = threadIdx.x;
  const int wv = tid >> 6, ln = tid & 63;
  const int m = ln & 15, quad = ln >> 4;
  const long t0 = (long)blockIdx.x * 64;
  const int row0 = wv * 16 + quad * 4;

  for (int i = tid; i < 30720 / 4; i += 256) ((uint32_t*)smem)[i] = 0;

  // fc1
  f4v acc1[8];
#pragma unroll
  for (int i = 0; i < 8; ++i) acc1[i] = (f4v){0.f, 0.f, 0.f, 0.f};
  for (int s = 0; s < 13; ++s) {
    {
      int r = tid >> 2, c0 = (tid & 3) * 8;
      *(uint4*)(xs + r * 40 + c0) =
          *(const uint4*)(p2 + (t0 + r) * 416 + s * 32 + c0);
      int n = tid >> 1, cw = (tid & 1) * 16;
      *(uint4*)(wbuf + n * 40 + cw) = *(const uint4*)(fc1t + (long)n * 416 + s * 32 + cw);
      *(uint4*)(wbuf + n * 40 + cw + 8) =
          *(const uint4*)(fc1t + (long)n * 416 + s * 32 + cw + 8);
    }
    __syncthreads();
    s8v a = *(const s8v*)(xs + (wv * 16 + m) * 40 + quad * 8);
#pragma unroll
    for (int nt = 0; nt < 8; ++nt) {
      s8v b = *(const s8v*)(wbuf + (nt * 16 + m) * 40 + quad * 8);
      acc1[nt] = __builtin_amdgcn_mfma_f32_16x16x32_bf16(a, b, acc1[nt], 0, 0, 0);
    }
    __syncthreads();
  }
#pragma unroll
  for (int nt = 0; nt < 8; ++nt) {
    int n = nt * 16 + m;
    if (n < 120) {
      float bv = In<INF32>::ld(fc1b, n);
#pragma unroll
      for (int r = 0; r < 4; ++r)
        hs[(row0 + r) * 136 + n] = f2bu(fmaxf(acc1[nt][r] + bv, 0.f));
    }
  }
  __syncthreads();

  // fc2
  for (int i = tid; i < 1536; i += 256) {
    int n = i >> 4, c0 = (i & 15) * 8;
    *(uint4*)(wbuf + n * 136 + c0) = *(const uint4*)(fc2t + n * 128 + c0);
  }
  __syncthreads();
  f4v acc2[6];
#pragma unroll
  for (int i = 0; i < 6; ++i) acc2[i] = (f4v){0.f, 0.f, 0.f, 0.f};
  for (int s = 0; s < 4; ++s) {
    s8v a = *(const s8v*)(hs + (wv * 16 + m) * 136 + s * 32 + quad * 8);
#pragma unroll
    for (int nt = 0; nt < 6; ++nt) {
      s8v b = *(const s8v*)(wbuf + (nt * 16 + m) * 136 + s * 32 + quad * 8);
      acc2[nt] = __builtin_amdgcn_mfma_f32_16x16x32_bf16(a, b, acc2[nt], 0, 0, 0);
    }
  }
  __syncthreads();
#pragma unroll
  for (int nt = 0; nt < 6; ++nt) {
    int n = nt * 16 + m;
    if (n < 84) {
      float bv = In<INF32>::ld(fc2b, n);
#pragma unroll
      for (int r = 0; r < 4; ++r)
        a2s[(row0 + r) * 104 + n] = f2bu(fmaxf(acc2[nt][r] + bv, 0.f));
    }
  }
  __syncthreads();

  // gate + writeback
  if (tid < 64) {
    const u16* xr = a2s + tid * 104;
    float l0 = 0.f, l1 = 0.f;
    for (int k = 0; k < 84; ++k) {
      float xv = bu2f(xr[k]);
      l0 = fmaf(xv, In<INF32>::ld(gw, 2 * k), l0);
      l1 = fmaf(xv, In<INF32>::ld(gw, 2 * k + 1), l1);
    }
    float mx = fmaxf(l0, l1);
    float e0 = __expf(l0 - mx), e1 = __expf(l1 - mx);
    float inv = 1.f / (e0 + e1);
    *(float2*)(scbuf + (t0 + tid) * 2) = make_float2(e0 * inv, e1 * inv);
  }
  for (int i = tid; i < 832; i += 256) {  // 64 rows x 13 uint4
    int r = i / 13, c0 = (i - r * 13) * 8;
    *(uint4*)(a2buf + (t0 + r) * 104 + c0) = *(const uint4*)(a2s + r * 104 + c0);
  }
}

// ---------------------------------------------------------------------------
// exp v2: one expert per block (grid = [B/64, 2]) -> ybuf [2][B][96] f32.
// R6: latency-pipelined. A-fragments live in registers (a2s LDS removed);
// w1/w2 use separate LDS buffers (wbA/wbB); next chunk's weights are
// prefetched into registers EARLY (T14 issue-early/write-late) so global
// latency hides under the MFMA phases instead of serializing the loop.
// LDS 70,400 B -> 2 blocks/CU.
// ---------------------------------------------------------------------------
template <bool INF32>
__global__ __launch_bounds__(256) void k_exp(
    const int* __restrict__ flag,
    const u16* __restrict__ a2buf, const float* __restrict__ scbuf,
    const u16* __restrict__ w1t, const u16* __restrict__ w2t,
    const void* __restrict__ eb1, const void* __restrict__ eb2,
    float* __restrict__ ybuf, int Btok) {
  if (*flag != (INF32 ? 1 : 0)) return;
  __shared__ __align__(16) char smem[70400];
  u16* hs  = (u16*)smem;                    // [64][136] 17,408 B
  u16* wbA = (u16*)(smem + 17408);          // [128][104] 26,624 B (w1 chunk)
  u16* wbB = (u16*)(smem + 44032);          // [96][136]  26,112 B (w2 slice)
  float* scs = (float*)(smem + 70144);      // [64]

  const int tid = threadIdx.x;
  const int wv = tid >> 6, ln = tid & 63;
  const int m = ln & 15, quad = ln >> 4;
  const int e = blockIdx.y;
  const long t0 = (long)blockIdx.x * 64;
  const int row0 = wv * 16 + quad * 4;
  const u16* w1te = w1t + (long)e * 196608;
  const u16* w2te = w2t + (long)e * 196608;

  // A fragments in registers, reused across all 16 K-chunks.
  const u16* arow = a2buf + (t0 + wv * 16 + m) * 104 + quad * 8;
  s8v a0 = *(const s8v*)(arow);
  s8v a1 = *(const s8v*)(arow + 32);
  s8v a2f = *(const s8v*)(arow + 64);
  if (tid < 64) scs[tid] = scbuf[(t0 + tid) * 2 + e];

  // staging address splits (1536 uint4 per buffer, 6 per thread)
  int nlA[6], cA0[6], nB[6], cB0[6];
#pragma unroll
  for (int k = 0; k < 6; ++k) {
    int i2 = tid + k * 256;
    nlA[k] = i2 / 12; cA0[k] = (i2 - nlA[k] * 12) * 8;
    nB[k] = i2 >> 4;  cB0[k] = (i2 & 15) * 8;
  }
  uint4 R1[6], R2[6];
#pragma unroll
  for (int k = 0; k < 6; ++k)
    R1[k] = *(const uint4*)(w1te + (long)nlA[k] * 96 + cA0[k]);
#pragma unroll
  for (int k = 0; k < 6; ++k)
    R2[k] = *(const uint4*)(w2te + (long)nB[k] * 2048 + cB0[k]);
#pragma unroll
  for (int k = 0; k < 6; ++k)
    *(uint4*)(wbA + nlA[k] * 104 + cA0[k]) = R1[k];
  __syncthreads();                          // wbA(0) ready; R2(0) in regs

  f4v acce[6];
#pragma unroll
  for (int i = 0; i < 6; ++i) acce[i] = (f4v){0.f, 0.f, 0.f, 0.f};

  for (int c = 0; c < 16; ++c) {
    const int n0 = c * 128;
    if (c < 15) {  // prefetch next w1 chunk (R1 regs free since prev write)
#pragma unroll
      for (int k = 0; k < 6; ++k)
        R1[k] = *(const uint4*)(w1te + (long)(n0 + 128 + nlA[k]) * 96 + cA0[k]);
    }
    // C_h: h = relu(a * w1chunk + b1)
    f4v acch[8];
#pragma unroll
    for (int i = 0; i < 8; ++i) acch[i] = (f4v){0.f, 0.f, 0.f, 0.f};
#pragma unroll
    for (int s = 0; s < 3; ++s) {
      s8v a = (s == 0) ? a0 : (s == 1) ? a1 : a2f;
#pragma unroll
      for (int nt = 0; nt < 8; ++nt) {
        s8v b = *(const s8v*)(wbA + (nt * 16 + m) * 104 + s * 32 + quad * 8);
        acch[nt] = __builtin_amdgcn_mfma_f32_16x16x32_bf16(a, b, acch[nt], 0, 0, 0);
      }
    }
#pragma unroll
    for (int nt = 0; nt < 8; ++nt) {
      float bv = In<INF32>::ld(eb1, (long)e * 2048 + n0 + nt * 16 + m);
#pragma unroll
      for (int r = 0; r < 4; ++r)
        hs[(row0 + r) * 136 + nt * 16 + m] = f2bu(fmaxf(acch[nt][r] + bv, 0.f));
    }
    __syncthreads();          // hs ready; all waves done reading wbA
#pragma unroll
    for (int k = 0; k < 6; ++k)
      *(uint4*)(wbB + nB[k] * 136 + cB0[k]) = R2[k];
    __syncthreads();          // wbB(c) ready
    if (c < 15) {  // prefetch next w2 slice (R2 regs free)
#pragma unroll
      for (int k = 0; k < 6; ++k)
        R2[k] = *(const uint4*)(w2te + (long)nB[k] * 2048 + n0 + 128 + cB0[k]);
    }
    // C_y: acce += h * w2slice
#pragma unroll
    for (int s = 0; s < 4; ++s) {
      s8v a = *(const s8v*)(hs + (wv * 16 + m) * 136 + s * 32 + quad * 8);
#pragma unroll
      for (int nt = 0; nt < 6; ++nt) {
        s8v b = *(const s8v*)(wbB + (nt * 16 + m) * 136 + s * 32 + quad * 8);
        acce[nt] = __builtin_amdgcn_mfma_f32_16x16x32_bf16(a, b, acce[nt], 0, 0, 0);
      }
    }
    __syncthreads();          // done reading wbB & hs
    if (c < 15) {
#pragma unroll
      for (int k = 0; k < 6; ++k)
        *(uint4*)(wbA + nlA[k] * 104 + cA0[k]) = R1[k];
      __syncthreads();        // wbA(c+1) ready for next C_h
    }
  }

  // y_e = sc * (acce + b2) -> ybuf
#pragma unroll
  for (int nt = 0; nt < 6; ++nt) {
    int d = nt * 16 + m;
    float bv = (d < 84) ? In<INF32>::ld(eb2, (long)e * 84 + d) : 0.f;
#pragma unroll
    for (int r = 0; r < 4; ++r) {
      float sc = scs[row0 + r];
      ybuf[((size_t)e * Btok + t0 + row0 + r) * 96 + d] = sc * (acce[nt][r] + bv);
    }
  }
}

// ---------------------------------------------------------------------------
// fc3: out = (y0 + y1) @ w3 + b3. 64 tokens/block.
// ---------------------------------------------------------------------------
template <bool INF32>
__global__ __launch_bounds__(256) void k_fc3(
    const int* __restrict__ flag,
    const float* __restrict__ ybuf,
    const void* __restrict__ w3, const void* __restrict__ b3,
    void* __restrict__ out, int Btok) {
  if (*flag != (INF32 ? 1 : 0)) return;
  __shared__ float sw3[840];
  __shared__ float sb3[10];
  const int tid = threadIdx.x;
  const long t0 = (long)blockIdx.x * 64;
  for (int i = tid; i < 840; i += 256) sw3[i] = In<INF32>::ld(w3, i);
  if (tid < 10) sb3[tid] = In<INF32>::ld(b3, tid);
  __syncthreads();
  for (int idx = tid; idx < 640; idx += 256) {
    int tk = idx / 10, cc = idx - tk * 10;
    const float* y0r = ybuf + (t0 + tk) * 96;
    const float* y1r = ybuf + ((size_t)Btok + t0 + tk) * 96;
    float acc = sb3[cc];
    for (int d = 0; d < 84; ++d)
      acc = fmaf(y0r[d] + y1r[d], sw3[d * 10 + cc], acc);
    long oi = (t0 + tk) * 10 + cc;
    if (INF32) ((float*)out)[oi] = acc;
    else ((u16*)out)[oi] = f2bu(acc);
  }
}

// ---------------------------------------------------------------------------
extern "C" void kernel_launch(void* const* d_in, const int* in_sizes, int n_in,
                              void* d_out, int out_size, void* d_ws, size_t ws_size,
                              hipStream_t stream) {
  const int B = in_sizes[0] / 3072;  // 16384
  char* wsb = (char*)d_ws;
  int* flag = (int*)wsb;
  u16* p2 = (u16*)(wsb + 64);                    // [B][416] bf16
  u16* fc1t = p2 + (size_t)B * 416;              // 53,248 elems
  u16* fc2t = fc1t + 53248;                      // 12,288
  u16* w1t = fc2t + 12288;                       // 393,216
  u16* w2t = w1t + 393216;                       // 393,216
  uint32_t* cdw = (uint32_t*)(w2t + 393216);     // 2,326 dwords
  u16* a2buf = (u16*)(cdw + 2326);               // [B][104] bf16
  float* scbuf = (float*)(a2buf + (size_t)B * 104);  // [B][2] f32
  float* ybuf = scbuf + (size_t)B * 2;           // [2][B][96] f32

  k_detect<<<1, 64, 0, stream>>>((const u16*)d_in[0], flag);

  // 856,598 work items -> 3347 blocks (tail 22 items are the conv biases).
  k_trans<false><<<3347, 256, 0, stream>>>(flag, d_in[5], d_in[7], d_in[10],
                                           d_in[12], d_in[1], d_in[2], d_in[3],
                                           d_in[4], fc1t, fc2t, w1t, w2t, cdw);
  k_trans<true><<<3347, 256, 0, stream>>>(flag, d_in[5], d_in[7], d_in[10],
                                          d_in[12], d_in[1], d_in[2], d_in[3],
                                          d_in[4], fc1t, fc2t, w1t, w2t, cdw);

  const int convGrid = (B + CIMG - 1) / CIMG;
  k_conv<false><<<convGrid, 256, 0, stream>>>(flag, d_in[0], cdw, p2, B);
  k_conv<true><<<convGrid, 256, 0, stream>>>(flag, d_in[0], cdw, p2, B);

  k_fcA<false><<<B / 64, 256, 0, stream>>>(flag, p2, fc1t, fc2t, d_in[6],
                                           d_in[8], d_in[9], a2buf, scbuf);
  k_fcA<true><<<B / 64, 256, 0, stream>>>(flag, p2, fc1t, fc2t, d_in[6],
                                          d_in[8], d_in[9], a2buf, scbuf);

  dim3 eg(B / 64, 2);
  k_exp<false><<<eg, 256, 0, stream>>>(flag, a2buf, scbuf, w1t, w2t, d_in[11],
                                       d_in[13], ybuf, B);
  k_exp<true><<<eg, 256, 0, stream>>>(flag, a2buf, scbuf, w1t, w2t, d_in[11],
                                      d_in[13], ybuf, B);

  k_fc3<false><<<B / 64, 256, 0, stream>>>(flag, ybuf, d_in[14], d_in[15],
                                           d_out, B);
  k_fc3<true><<<B / 64, 256, 0, stream>>>(flag, ybuf, d_in[14], d_in[15],
                                          d_out, B);
}

// Round 7
// 499.773 us; speedup vs baseline: 1.1575x; 1.1575x over previous
//
#include <hip/hip_runtime.h>
#include <stdint.h>

typedef unsigned short u16;
typedef __attribute__((ext_vector_type(8))) short s8v;    // 8 x bf16
typedef __attribute__((ext_vector_type(4))) float f4v;    // 4 x f32
typedef __fp16 h2v __attribute__((ext_vector_type(2)));   // 2 x f16
typedef __fp16 h8v __attribute__((ext_vector_type(8)));   // 8 x f16

__device__ __forceinline__ float bu2f(u16 u) {
  return __uint_as_float(((uint32_t)u) << 16);
}
__device__ __forceinline__ u16 f2bu(float f) {
  uint32_t u = __float_as_uint(f);
  u += 0x7fffu + ((u >> 16) & 1u);  // RNE
  return (u16)(u >> 16);
}

union U32H2 { uint32_t u; h2v h; };

__device__ __forceinline__ uint32_t pk2h(float a, float b) {
  U32H2 x;
  x.h = __builtin_amdgcn_cvt_pkrtz(a, b);  // exact for bf16-valued inputs
  return x.u;
}

// ---- input dtype abstraction ----------------------------------------------
template <bool F32> struct In;
template <> struct In<true> {
  static __device__ __forceinline__ float ld(const void* p, long i) {
    return ((const float*)p)[i];
  }
};
template <> struct In<false> {
  static __device__ __forceinline__ float ld(const void* p, long i) {
    return bu2f(((const u16*)p)[i]);
  }
};

// ---- dtype detector (proven) ----------------------------------------------
__global__ void k_detect(const u16* __restrict__ x, int* __restrict__ flag) {
  __shared__ int s[64];
  int cnt = 0;
  for (int i = threadIdx.x; i < 2048; i += 64) {
    int e = (x[i] >> 7) & 0xFF;
    cnt += (e >= 96 && e <= 134) ? 1 : 0;
  }
  s[threadIdx.x] = cnt;
  __syncthreads();
  if (threadIdx.x == 0) {
    int t = 0;
    for (int i = 0; i < 64; ++i) t += s[i];
    *flag = (t >= 1843) ? 0 : 1;  // 0 = bf16, 1 = f32
  }
}

// ---------------------------------------------------------------------------
// Weight transforms into ws:
//  fc1t [128][416] bf16, fc2t [96][128] bf16, w1t [2][2048][96] bf16,
//  w2t [2][96][2048] bf16,
//  cdw: MFMA conv weights: cd1m[3][64][8] f16, cd2m[6][64][8] f16,
//       cb1[6] f32 @dword 2304, cb2[16] f32 @dword 2310. Total 2326 dwords.
// Tap order for conv MFMA (row-padded to 6): t = quad*8 + j,
//   ky = t/6, kxp = t%6; weight 0 for kxp==5 or t>=30 (and n>=6 for conv1).
// ---------------------------------------------------------------------------
__device__ __forceinline__ u16 f2h16(float f) {
  __fp16 h = (__fp16)f;
  u16 r;
  __builtin_memcpy(&r, &h, 2);
  return r;
}

template <bool INF32>
__global__ __launch_bounds__(256) void k_trans(
    const int* __restrict__ flag,
    const void* __restrict__ fc1w, const void* __restrict__ fc2w,
    const void* __restrict__ ew1, const void* __restrict__ ew2,
    const void* __restrict__ c1w, const void* __restrict__ c1b,
    const void* __restrict__ c2w, const void* __restrict__ c2b,
    u16* __restrict__ fc1t, u16* __restrict__ fc2t,
    u16* __restrict__ w1t, u16* __restrict__ w2t,
    uint32_t* __restrict__ cdw) {
  if (*flag != (INF32 ? 1 : 0)) return;
  long gid = (long)blockIdx.x * 256 + threadIdx.x;
  if (gid < 53248) {                       // fc1t: [128 n][416 k]
    int n = (int)(gid / 416), k = (int)(gid % 416);
    fc1t[gid] = (n < 120 && k < 400) ? f2bu(In<INF32>::ld(fc1w, (long)k * 120 + n)) : (u16)0;
  } else if (gid < 65536) {                // fc2t: [96 n][128 k]
    long i = gid - 53248;
    int n = (int)(i / 128), k = (int)(i % 128);
    fc2t[i] = (n < 84 && k < 120) ? f2bu(In<INF32>::ld(fc2w, (long)k * 84 + n)) : (u16)0;
  } else if (gid < 458752) {               // w1t: [2][2048 n][96 k]
    long i = gid - 65536;
    int e = (int)(i / 196608);
    long r = i % 196608;
    int n = (int)(r / 96), k = (int)(r % 96);
    w1t[i] = (k < 84) ? f2bu(In<INF32>::ld(ew1, ((long)e * 84 + k) * 2048 + n)) : (u16)0;
  } else if (gid < 851968) {               // w2t: [2][96 n][2048 k]
    long i = gid - 458752;
    int e = (int)(i / 196608);
    long r = i % 196608;
    int n = (int)(r / 2048), k = (int)(r % 2048);
    w2t[i] = (n < 84) ? f2bu(In<INF32>::ld(ew2, ((long)e * 2048 + k) * 84 + n)) : (u16)0;
  } else if (gid < 856598) {               // conv MFMA weights + biases
    long i = gid - 851968;
    u16* cdh = (u16*)cdw;
    if (i < 1536) {          // cd1m [3 ic][64 lane][8 j]
      int ic = (int)(i >> 9);
      int r = (int)(i & 511);
      int lnn = r >> 3, j = r & 7;
      int n = lnn & 15, qd = lnn >> 4;
      int t = qd * 8 + j, ky = t / 6, kxp = t - ky * 6;
      float v = (n < 6 && t < 30 && kxp < 5)
          ? In<INF32>::ld(c1w, ((long)(n * 3 + ic) * 5 + ky) * 5 + kxp) : 0.f;
      cdh[i] = f2h16(v);
    } else if (i < 4608) {   // cd2m [6 ic][64 lane][8 j]
      long jj = i - 1536;
      int ic = (int)(jj >> 9);
      int r = (int)(jj & 511);
      int lnn = r >> 3, j = r & 7;
      int n = lnn & 15, qd = lnn >> 4;
      int t = qd * 8 + j, ky = t / 6, kxp = t - ky * 6;
      float v = (t < 30 && kxp < 5)
          ? In<INF32>::ld(c2w, ((long)(n * 6 + ic) * 5 + ky) * 5 + kxp) : 0.f;
      cdh[1536 + jj] = f2h16(v);
    } else if (i < 4614) {   // cb1 (f32)
      ((float*)(cdw + 2304))[i - 4608] = In<INF32>::ld(c1b, i - 4608);
    } else if (i < 4630) {   // cb2 (f32)
      ((float*)(cdw + 2310))[i - 4614] = In<INF32>::ld(c2b, i - 4614);
    }
  }
}

// ---------------------------------------------------------------------------
// Conv kernel v6: MFMA implicit-GEMM, bank-decongruent shifted copies.
//   R7: sxs placed at +8 banks from sxn (pad 16 u16; sxn is 3264 dw == 0
//   mod 32) so dxA=0/1 lanes hit disjoint bank sets ({0..3,17..20} vs
//   {8..11,25..28}); sp1s at +16 banks (its footprint {0..3,9..12} needs a
//   +16 shift for disjointness). Worst-case multiplicity ~6 -> 3.
// Out p2: [B][416] bf16, cols 400..415 zero.
// ---------------------------------------------------------------------------
#define CIMG 2
#define XSTR 34           // sx row stride (elems); 17 dw (odd)
#define PSTR 18           // sp1 row stride (elems); 9 dw (odd)
#define SXELEMS (CIMG * 3 * 32 * XSTR)   // 6528 u16 = 3264 dw == 0 (mod 32)
#define SPELEMS (CIMG * 6 * 14 * PSTR)   // 3024 u16 = 1512 dw == 8 (mod 32)
template <bool INF32>
__global__ __launch_bounds__(256) void k_conv(
    const int* __restrict__ flag,
    const void* __restrict__ x,
    const uint32_t* __restrict__ cdw,
    u16* __restrict__ p2, int Btot) {
  if (*flag != (INF32 ? 1 : 0)) return;
  __shared__ __align__(16) u16 sxbuf[2 * SXELEMS + 16];   // sxs at +8 banks
  __shared__ __align__(16) u16 sp1buf[2 * SPELEMS + 16];  // sp1s at +16 banks
  __shared__ u16 lut1[196];
  __shared__ u16 lut2[32];
  u16* sxn = sxbuf;
  u16* sxs = sxbuf + SXELEMS + 16;    // dw 3272 == 8 (mod 32)
  u16* sp1n = sp1buf;
  u16* sp1s = sp1buf + SPELEMS + 16;  // dw 1520 == 16 (mod 32)
  const u16* cdh = (const u16*)cdw;
  const float* cb1f = (const float*)(cdw + 2304);
  const float* cb2f = (const float*)(cdw + 2310);
  const int tid = threadIdx.x;
  const int wv = tid >> 6, ln = tid & 63;
  const int mrow = ln & 15, quad = ln >> 4;
  const long gimg0 = (long)blockIdx.x * CIMG;

  if (tid < 196) {
    int py = tid / 14, px = tid - py * 14;
    lut1[tid] = (u16)((2 * py) * XSTR + 2 * px);
  } else if (tid < 228) {
    int i = tid - 196;
    if (i < 25) {
      int py = i / 5, px = i - py * 5;
      lut2[i] = (u16)((2 * py) * PSTR + 2 * px);
    }
  }
  for (int r = tid; r < CIMG * 6 * 14; r += 256)
    *(uint32_t*)(sp1s + (size_t)r * PSTR + 12) = 0;

  for (int i = tid; i < CIMG * 96; i += 256) {
    int img = i / 96;
    if (gimg0 + img >= Btot) continue;
    int rem = i - img * 96;
    long goff = (gimg0 + img) * 3072 + (long)rem * 32;
    uint32_t e[17];
    if (!INF32) {
      const uint32_t* src = (const uint32_t*)((const u16*)x + goff);
#pragma unroll
      for (int j = 0; j < 16; ++j) {
        uint32_t d = src[j];
        e[j] = pk2h(__uint_as_float(d << 16), __uint_as_float(d & 0xffff0000u));
      }
    } else {
      const float* src = (const float*)x + goff;
#pragma unroll
      for (int j = 0; j < 16; ++j) e[j] = pk2h(src[2 * j], src[2 * j + 1]);
    }
    e[16] = 0;
    uint32_t* dn = (uint32_t*)(sxn + (size_t)i * XSTR);
    uint32_t* dsh = (uint32_t*)(sxs + (size_t)i * XSTR);
#pragma unroll
    for (int j = 0; j < 16; ++j) {
      dn[j] = e[j];
      dsh[j] = (e[j] >> 16) | (e[j + 1] << 16);
    }
  }

  h8v b1[3];
#pragma unroll
  for (int ic = 0; ic < 3; ++ic)
    b1[ic] = *(const h8v*)(cdh + ((size_t)ic * 64 + ln) * 8);
  const float bias1 = (mrow < 6) ? cb1f[mrow] : 0.f;
  int toff1[4];
#pragma unroll
  for (int p = 0; p < 4; ++p) {
    int t = quad * 8 + 2 * p;
    if (t >= 30) t = 24;
    toff1[p] = (t / 6) * (XSTR - 6) + t;
  }
  const int qA = mrow >> 2, dyA = (mrow >> 1) & 1, dxA = mrow & 1;

  __syncthreads();

  const u16* c1base = dxA ? sxs : sxn;
  for (int tg = wv; tg < CIMG * 49; tg += 4) {
    int img = tg / 49, tau = tg - img * 49;
    int pqA = tau * 4 + qA;
    const u16* rb0 = c1base + (size_t)img * (3 * 32 * XSTR) + lut1[pqA] + dyA * XSTR;
    f4v acc = {0.f, 0.f, 0.f, 0.f};
#pragma unroll
    for (int ic = 0; ic < 3; ++ic) {
      const u16* rb = rb0 + ic * (32 * XSTR);
      union { uint32_t w[4]; h8v v; } au;
#pragma unroll
      for (int p = 0; p < 4; ++p)
        au.w[p] = *(const uint32_t*)(rb + toff1[p]);
      acc = __builtin_amdgcn_mfma_f32_16x16x32_f16(au.v, b1[ic], acc, 0, 0, 0);
    }
    float v = fmaxf(fmaxf(acc[0], acc[1]), fmaxf(acc[2], acc[3])) + bias1;
    v = fmaxf(v, 0.f);
    if (mrow < 6) {
      int pqC = tau * 4 + quad;
      int py = (pqC * 4682) >> 16, px = pqC - py * 14;
      int rbase = ((img * 6 + mrow) * 14 + py) * PSTR;
      u16 hv = f2h16(v);
      sp1n[rbase + px] = hv;
      sp1s[rbase + (px ? px - 1 : PSTR - 1)] = hv;
    }
  }

  h8v b2[6];
#pragma unroll
  for (int ic = 0; ic < 6; ++ic)
    b2[ic] = *(const h8v*)(cdh + 1536 + ((size_t)ic * 64 + ln) * 8);
  const float bias2 = cb2f[mrow];
  int toff2[4];
#pragma unroll
  for (int p = 0; p < 4; ++p) {
    int t = quad * 8 + 2 * p;
    if (t >= 30) t = 24;
    toff2[p] = (t / 6) * (PSTR - 6) + t;
  }

  __syncthreads();

  const int NP2 = CIMG * 25;
  const u16* c2base = dxA ? sp1s : sp1n;
  for (int t2 = wv; t2 * 4 < NP2; t2 += 4) {
    int PA = t2 * 4 + qA;
    if (PA >= NP2) PA = NP2 - 1;
    int img = (PA * 41) >> 10, pq = PA - img * 25;
    const u16* rb0 = c2base + (size_t)img * (6 * 14 * PSTR) + lut2[pq] + dyA * PSTR;
    f4v acc = {0.f, 0.f, 0.f, 0.f};
#pragma unroll
    for (int ic = 0; ic < 6; ++ic) {
      const u16* rb = rb0 + ic * (14 * PSTR);
      union { uint32_t w[4]; h8v v; } au;
#pragma unroll
      for (int p = 0; p < 4; ++p)
        au.w[p] = *(const uint32_t*)(rb + toff2[p]);
      acc = __builtin_amdgcn_mfma_f32_16x16x32_f16(au.v, b2[ic], acc, 0, 0, 0);
    }
    float v = fmaxf(fmaxf(acc[0], acc[1]), fmaxf(acc[2], acc[3])) + bias2;
    v = fmaxf(v, 0.f);
    int PC = t2 * 4 + quad;
    if (PC < NP2) {
      int imgc = (PC * 41) >> 10, pqc = PC - imgc * 25;
      if (gimg0 + imgc < Btot)
        p2[(gimg0 + imgc) * 416 + mrow * 25 + pqc] = f2bu(v);
    }
  }

  for (int i = tid; i < CIMG * 16; i += 256) {
    int img = i / 16;
    if (gimg0 + img < Btot) p2[(gimg0 + img) * 416 + 400 + (i & 15)] = 0;
  }
}

// ---------------------------------------------------------------------------
// fcA: fc1 -> fc2 -> gate. 64 tokens/block (unchanged).
// ---------------------------------------------------------------------------
template <bool INF32>
__global__ __launch_bounds__(256) void k_fcA(
    const int* __restrict__ flag,
    const u16* __restrict__ p2,
    const u16* __restrict__ fc1t, const u16* __restrict__ fc2t,
    const void* __restrict__ fc1b, const void* __restrict__ fc2b,
    const void* __restrict__ gw,
    u16* __restrict__ a2buf, float* __restrict__ scbuf) {
  if (*flag != (INF32 ? 1 : 0)) return;
  __shared__ __align__(16) char smem[62976];
  u16* a2s = (u16*)smem;                    // [64][104]
  u16* hs = (u16*)(smem + 13312);           // [64][136]
  u16* wbuf = (u16*)(smem + 31232);
  u16* xs = (u16*)(smem + 57856);           // [64][40]

  const int tid = threadIdx.x;
  const int wv = tid >> 6, ln = tid & 63;
  const int m = ln & 15, quad = ln >> 4;
  const long t0 = (long)blockIdx.x * 64;
  const int row0 = wv * 16 + quad * 4;

  for (int i = tid; i < 30720 / 4; i += 256) ((uint32_t*)smem)[i] = 0;

  // fc1
  f4v acc1[8];
#pragma unroll
  for (int i = 0; i < 8; ++i) acc1[i] = (f4v){0.f, 0.f, 0.f, 0.f};
  for (int s = 0; s < 13; ++s) {
    {
      int r = tid >> 2, c0 = (tid & 3) * 8;
      *(uint4*)(xs + r * 40 + c0) =
          *(const uint4*)(p2 + (t0 + r) * 416 + s * 32 + c0);
      int n = tid >> 1, cw = (tid & 1) * 16;
      *(uint4*)(wbuf + n * 40 + cw) = *(const uint4*)(fc1t + (long)n * 416 + s * 32 + cw);
      *(uint4*)(wbuf + n * 40 + cw + 8) =
          *(const uint4*)(fc1t + (long)n * 416 + s * 32 + cw + 8);
    }
    __syncthreads();
    s8v a = *(const s8v*)(xs + (wv * 16 + m) * 40 + quad * 8);
#pragma unroll
    for (int nt = 0; nt < 8; ++nt) {
      s8v b = *(const s8v*)(wbuf + (nt * 16 + m) * 40 + quad * 8);
      acc1[nt] = __builtin_amdgcn_mfma_f32_16x16x32_bf16(a, b, acc1[nt], 0, 0, 0);
    }
    __syncthreads();
  }
#pragma unroll
  for (int nt = 0; nt < 8; ++nt) {
    int n = nt * 16 + m;
    if (n < 120) {
      float bv = In<INF32>::ld(fc1b, n);
#pragma unroll
      for (int r = 0; r < 4; ++r)
        hs[(row0 + r) * 136 + n] = f2bu(fmaxf(acc1[nt][r] + bv, 0.f));
    }
  }
  __syncthreads();

  // fc2
  for (int i = tid; i < 1536; i += 256) {
    int n = i >> 4, c0 = (i & 15) * 8;
    *(uint4*)(wbuf + n * 136 + c0) = *(const uint4*)(fc2t + n * 128 + c0);
  }
  __syncthreads();
  f4v acc2[6];
#pragma unroll
  for (int i = 0; i < 6; ++i) acc2[i] = (f4v){0.f, 0.f, 0.f, 0.f};
  for (int s = 0; s < 4; ++s) {
    s8v a = *(const s8v*)(hs + (wv * 16 + m) * 136 + s * 32 + quad * 8);
#pragma unroll
    for (int nt = 0; nt < 6; ++nt) {
      s8v b = *(const s8v*)(wbuf + (nt * 16 + m) * 136 + s * 32 + quad * 8);
      acc2[nt] = __builtin_amdgcn_mfma_f32_16x16x32_bf16(a, b, acc2[nt], 0, 0, 0);
    }
  }
  __syncthreads();
#pragma unroll
  for (int nt = 0; nt < 6; ++nt) {
    int n = nt * 16 + m;
    if (n < 84) {
      float bv = In<INF32>::ld(fc2b, n);
#pragma unroll
      for (int r = 0; r < 4; ++r)
        a2s[(row0 + r) * 104 + n] = f2bu(fmaxf(acc2[nt][r] + bv, 0.f));
    }
  }
  __syncthreads();

  // gate + writeback
  if (tid < 64) {
    const u16* xr = a2s + tid * 104;
    float l0 = 0.f, l1 = 0.f;
    for (int k = 0; k < 84; ++k) {
      float xv = bu2f(xr[k]);
      l0 = fmaf(xv, In<INF32>::ld(gw, 2 * k), l0);
      l1 = fmaf(xv, In<INF32>::ld(gw, 2 * k + 1), l1);
    }
    float mx = fmaxf(l0, l1);
    float e0 = __expf(l0 - mx), e1 = __expf(l1 - mx);
    float inv = 1.f / (e0 + e1);
    *(float2*)(scbuf + (t0 + tid) * 2) = make_float2(e0 * inv, e1 * inv);
  }
  for (int i = tid; i < 832; i += 256) {  // 64 rows x 13 uint4
    int r = i / 13, c0 = (i - r * 13) * 8;
    *(uint4*)(a2buf + (t0 + r) * 104 + c0) = *(const uint4*)(a2s + r * 104 + c0);
  }
}

// ---------------------------------------------------------------------------
// exp: one expert per block (grid = [B/64, 2]) -> ybuf [2][B][96] f32.
// R7: reverted to the R5-proven version (R6's reg-prefetch pipeline was a
// 36 us regression -- TLP was already hiding the staging latency).
// ---------------------------------------------------------------------------
template <bool INF32>
__global__ __launch_bounds__(256) void k_exp(
    const int* __restrict__ flag,
    const u16* __restrict__ a2buf, const float* __restrict__ scbuf,
    const u16* __restrict__ w1t, const u16* __restrict__ w2t,
    const void* __restrict__ eb1, const void* __restrict__ eb2,
    float* __restrict__ ybuf, int Btok) {
  if (*flag != (INF32 ? 1 : 0)) return;
  __shared__ __align__(16) char smem[57856];
  u16* a2s = (u16*)smem;                    // [64][104]
  u16* hs = (u16*)(smem + 13312);           // [64][136]
  u16* wbuf = (u16*)(smem + 30720);         // 26,624 B
  float* scs = (float*)(smem + 57344);      // [64]

  const int tid = threadIdx.x;
  const int wv = tid >> 6, ln = tid & 63;
  const int m = ln & 15, quad = ln >> 4;
  const int e = blockIdx.y;
  const long t0 = (long)blockIdx.x * 64;
  const int row0 = wv * 16 + quad * 4;
  const u16* w1te = w1t + (long)e * 196608;
  const u16* w2te = w2t + (long)e * 196608;

  for (int i = tid; i < 832; i += 256) {
    int r = i / 13, c0 = (i - r * 13) * 8;
    *(uint4*)(a2s + r * 104 + c0) = *(const uint4*)(a2buf + (t0 + r) * 104 + c0);
  }
  if (tid < 64) scs[tid] = scbuf[(t0 + tid) * 2 + e];
  __syncthreads();

  f4v acce[6];
#pragma unroll
  for (int i = 0; i < 6; ++i) acce[i] = (f4v){0.f, 0.f, 0.f, 0.f};
  for (int c = 0; c < 16; ++c) {
    const int n0 = c * 128;
    if (c) __syncthreads();
    for (int i = tid; i < 1536; i += 256) {  // wbuf[128][104] <- w1t chunk
      int nl = i / 12, c0 = (i - nl * 12) * 8;
      *(uint4*)(wbuf + nl * 104 + c0) =
          *(const uint4*)(w1te + (long)(n0 + nl) * 96 + c0);
    }
    __syncthreads();
    f4v acch[8];
#pragma unroll
    for (int i = 0; i < 8; ++i) acch[i] = (f4v){0.f, 0.f, 0.f, 0.f};
    for (int s = 0; s < 3; ++s) {
      s8v a = *(const s8v*)(a2s + (wv * 16 + m) * 104 + s * 32 + quad * 8);
#pragma unroll
      for (int nt = 0; nt < 8; ++nt) {
        s8v b = *(const s8v*)(wbuf + (nt * 16 + m) * 104 + s * 32 + quad * 8);
        acch[nt] = __builtin_amdgcn_mfma_f32_16x16x32_bf16(a, b, acch[nt], 0, 0, 0);
      }
    }
#pragma unroll
    for (int nt = 0; nt < 8; ++nt) {
      float bv = In<INF32>::ld(eb1, (long)e * 2048 + n0 + nt * 16 + m);
#pragma unroll
      for (int r = 0; r < 4; ++r)
        hs[(row0 + r) * 136 + nt * 16 + m] = f2bu(fmaxf(acch[nt][r] + bv, 0.f));
    }
    __syncthreads();
    for (int i = tid; i < 1536; i += 256) {  // wbuf[96][136] <- w2t slice
      int n = i >> 4, c0 = (i & 15) * 8;
      *(uint4*)(wbuf + n * 136 + c0) =
          *(const uint4*)(w2te + (long)n * 2048 + n0 + c0);
    }
    __syncthreads();
    for (int s = 0; s < 4; ++s) {
      s8v a = *(const s8v*)(hs + (wv * 16 + m) * 136 + s * 32 + quad * 8);
#pragma unroll
      for (int nt = 0; nt < 6; ++nt) {
        s8v b = *(const s8v*)(wbuf + (nt * 16 + m) * 136 + s * 32 + quad * 8);
        acce[nt] = __builtin_amdgcn_mfma_f32_16x16x32_bf16(a, b, acce[nt], 0, 0, 0);
      }
    }
  }

  // y_e = sc * (acce + b2) -> ybuf
#pragma unroll
  for (int nt = 0; nt < 6; ++nt) {
    int d = nt * 16 + m;
    float bv = (d < 84) ? In<INF32>::ld(eb2, (long)e * 84 + d) : 0.f;
#pragma unroll
    for (int r = 0; r < 4; ++r) {
      float sc = scs[row0 + r];
      ybuf[((size_t)e * Btok + t0 + row0 + r) * 96 + d] = sc * (acce[nt][r] + bv);
    }
  }
}

// ---------------------------------------------------------------------------
// fc3: out = (y0 + y1) @ w3 + b3. 64 tokens/block.
// ---------------------------------------------------------------------------
template <bool INF32>
__global__ __launch_bounds__(256) void k_fc3(
    const int* __restrict__ flag,
    const float* __restrict__ ybuf,
    const void* __restrict__ w3, const void* __restrict__ b3,
    void* __restrict__ out, int Btok) {
  if (*flag != (INF32 ? 1 : 0)) return;
  __shared__ float sw3[840];
  __shared__ float sb3[10];
  const int tid = threadIdx.x;
  const long t0 = (long)blockIdx.x * 64;
  for (int i = tid; i < 840; i += 256) sw3[i] = In<INF32>::ld(w3, i);
  if (tid < 10) sb3[tid] = In<INF32>::ld(b3, tid);
  __syncthreads();
  for (int idx = tid; idx < 640; idx += 256) {
    int tk = idx / 10, cc = idx - tk * 10;
    const float* y0r = ybuf + (t0 + tk) * 96;
    const float* y1r = ybuf + ((size_t)Btok + t0 + tk) * 96;
    float acc = sb3[cc];
    for (int d = 0; d < 84; ++d)
      acc = fmaf(y0r[d] + y1r[d], sw3[d * 10 + cc], acc);
    long oi = (t0 + tk) * 10 + cc;
    if (INF32) ((float*)out)[oi] = acc;
    else ((u16*)out)[oi] = f2bu(acc);
  }
}

// ---------------------------------------------------------------------------
extern "C" void kernel_launch(void* const* d_in, const int* in_sizes, int n_in,
                              void* d_out, int out_size, void* d_ws, size_t ws_size,
                              hipStream_t stream) {
  const int B = in_sizes[0] / 3072;  // 16384
  char* wsb = (char*)d_ws;
  int* flag = (int*)wsb;
  u16* p2 = (u16*)(wsb + 64);                    // [B][416] bf16
  u16* fc1t = p2 + (size_t)B * 416;              // 53,248 elems
  u16* fc2t = fc1t + 53248;                      // 12,288
  u16* w1t = fc2t + 12288;                       // 393,216
  u16* w2t = w1t + 393216;                       // 393,216
  uint32_t* cdw = (uint32_t*)(w2t + 393216);     // 2,326 dwords
  u16* a2buf = (u16*)(cdw + 2326);               // [B][104] bf16
  float* scbuf = (float*)(a2buf + (size_t)B * 104);  // [B][2] f32
  float* ybuf = scbuf + (size_t)B * 2;           // [2][B][96] f32

  k_detect<<<1, 64, 0, stream>>>((const u16*)d_in[0], flag);

  // 856,598 work items -> 3347 blocks (tail 22 items are the conv biases).
  k_trans<false><<<3347, 256, 0, stream>>>(flag, d_in[5], d_in[7], d_in[10],
                                           d_in[12], d_in[1], d_in[2], d_in[3],
                                           d_in[4], fc1t, fc2t, w1t, w2t, cdw);
  k_trans<true><<<3347, 256, 0, stream>>>(flag, d_in[5], d_in[7], d_in[10],
                                          d_in[12], d_in[1], d_in[2], d_in[3],
                                          d_in[4], fc1t, fc2t, w1t, w2t, cdw);

  const int convGrid = (B + CIMG - 1) / CIMG;
  k_conv<false><<<convGrid, 256, 0, stream>>>(flag, d_in[0], cdw, p2, B);
  k_conv<true><<<convGrid, 256, 0, stream>>>(flag, d_in[0], cdw, p2, B);

  k_fcA<false><<<B / 64, 256, 0, stream>>>(flag, p2, fc1t, fc2t, d_in[6],
                                           d_in[8], d_in[9], a2buf, scbuf);
  k_fcA<true><<<B / 64, 256, 0, stream>>>(flag, p2, fc1t, fc2t, d_in[6],
                                          d_in[8], d_in[9], a2buf, scbuf);

  dim3 eg(B / 64, 2);
  k_exp<false><<<eg, 256, 0, stream>>>(flag, a2buf, scbuf, w1t, w2t, d_in[11],
                                       d_in[13], ybuf, B);
  k_exp<true><<<eg, 256, 0, stream>>>(flag, a2buf, scbuf, w1t, w2t, d_in[11],
                                      d_in[13], ybuf, B);

  k_fc3<false><<<B / 64, 256, 0, stream>>>(flag, ybuf, d_in[14], d_in[15],
                                           d_out, B);
  k_fc3<true><<<B / 64, 256, 0, stream>>>(flag, ybuf, d_in[14], d_in[15],
                                          d_out, B);
}

// Round 9
// 497.121 us; speedup vs baseline: 1.1637x; 1.0053x over previous
//
#include <hip/hip_runtime.h>
#include <stdint.h>

typedef unsigned short u16;
typedef __attribute__((ext_vector_type(8))) short s8v;    // 8 x bf16
typedef __attribute__((ext_vector_type(4))) float f4v;    // 4 x f32
typedef __fp16 h2v __attribute__((ext_vector_type(2)));   // 2 x f16
typedef __fp16 h8v __attribute__((ext_vector_type(8)));   // 8 x f16

__device__ __forceinline__ float bu2f(u16 u) {
  return __uint_as_float(((uint32_t)u) << 16);
}
__device__ __forceinline__ u16 f2bu(float f) {
  uint32_t u = __float_as_uint(f);
  u += 0x7fffu + ((u >> 16) & 1u);  // RNE
  return (u16)(u >> 16);
}

union U32H2 { uint32_t u; h2v h; };

__device__ __forceinline__ uint32_t pk2h(float a, float b) {
  U32H2 x;
  x.h = __builtin_amdgcn_cvt_pkrtz(a, b);  // exact for bf16-valued inputs
  return x.u;
}

// ---- input dtype abstraction ----------------------------------------------
template <bool F32> struct In;
template <> struct In<true> {
  static __device__ __forceinline__ float ld(const void* p, long i) {
    return ((const float*)p)[i];
  }
};
template <> struct In<false> {
  static __device__ __forceinline__ float ld(const void* p, long i) {
    return bu2f(((const u16*)p)[i]);
  }
};

// ---- dtype detector (proven) ----------------------------------------------
__global__ void k_detect(const u16* __restrict__ x, int* __restrict__ flag) {
  __shared__ int s[64];
  int cnt = 0;
  for (int i = threadIdx.x; i < 2048; i += 64) {
    int e = (x[i] >> 7) & 0xFF;
    cnt += (e >= 96 && e <= 134) ? 1 : 0;
  }
  s[threadIdx.x] = cnt;
  __syncthreads();
  if (threadIdx.x == 0) {
    int t = 0;
    for (int i = 0; i < 64; ++i) t += s[i];
    *flag = (t >= 1843) ? 0 : 1;  // 0 = bf16, 1 = f32
  }
}

// ---------------------------------------------------------------------------
// Weight transforms into ws:
//  fc1t [128][416] bf16, fc2t [96][128] bf16, w1t [2][2048][96] bf16,
//  w2t [2][96][2048] bf16,
//  cdw: MFMA conv weights: cd1m[3][64][8] f16, cd2m[6][64][8] f16,
//       cb1[6] f32 @dword 2304, cb2[16] f32 @dword 2310. Total 2326 dwords.
// Tap order for conv MFMA (row-padded to 6): t = quad*8 + j,
//   ky = t/6, kxp = t%6; weight 0 for kxp==5 or t>=30 (and n>=6 for conv1).
// ---------------------------------------------------------------------------
__device__ __forceinline__ u16 f2h16(float f) {
  __fp16 h = (__fp16)f;
  u16 r;
  __builtin_memcpy(&r, &h, 2);
  return r;
}

template <bool INF32>
__global__ __launch_bounds__(256) void k_trans(
    const int* __restrict__ flag,
    const void* __restrict__ fc1w, const void* __restrict__ fc2w,
    const void* __restrict__ ew1, const void* __restrict__ ew2,
    const void* __restrict__ c1w, const void* __restrict__ c1b,
    const void* __restrict__ c2w, const void* __restrict__ c2b,
    u16* __restrict__ fc1t, u16* __restrict__ fc2t,
    u16* __restrict__ w1t, u16* __restrict__ w2t,
    uint32_t* __restrict__ cdw) {
  if (*flag != (INF32 ? 1 : 0)) return;
  long gid = (long)blockIdx.x * 256 + threadIdx.x;
  if (gid < 53248) {                       // fc1t: [128 n][416 k]
    int n = (int)(gid / 416), k = (int)(gid % 416);
    fc1t[gid] = (n < 120 && k < 400) ? f2bu(In<INF32>::ld(fc1w, (long)k * 120 + n)) : (u16)0;
  } else if (gid < 65536) {                // fc2t: [96 n][128 k]
    long i = gid - 53248;
    int n = (int)(i / 128), k = (int)(i % 128);
    fc2t[i] = (n < 84 && k < 120) ? f2bu(In<INF32>::ld(fc2w, (long)k * 84 + n)) : (u16)0;
  } else if (gid < 458752) {               // w1t: [2][2048 n][96 k]
    long i = gid - 65536;
    int e = (int)(i / 196608);
    long r = i % 196608;
    int n = (int)(r / 96), k = (int)(r % 96);
    w1t[i] = (k < 84) ? f2bu(In<INF32>::ld(ew1, ((long)e * 84 + k) * 2048 + n)) : (u16)0;
  } else if (gid < 851968) {               // w2t: [2][96 n][2048 k]
    long i = gid - 458752;
    int e = (int)(i / 196608);
    long r = i % 196608;
    int n = (int)(r / 2048), k = (int)(r % 2048);
    w2t[i] = (n < 84) ? f2bu(In<INF32>::ld(ew2, ((long)e * 2048 + k) * 84 + n)) : (u16)0;
  } else if (gid < 856598) {               // conv MFMA weights + biases
    long i = gid - 851968;
    u16* cdh = (u16*)cdw;
    if (i < 1536) {          // cd1m [3 ic][64 lane][8 j]
      int ic = (int)(i >> 9);
      int r = (int)(i & 511);
      int lnn = r >> 3, j = r & 7;
      int n = lnn & 15, qd = lnn >> 4;
      int t = qd * 8 + j, ky = t / 6, kxp = t - ky * 6;
      float v = (n < 6 && t < 30 && kxp < 5)
          ? In<INF32>::ld(c1w, ((long)(n * 3 + ic) * 5 + ky) * 5 + kxp) : 0.f;
      cdh[i] = f2h16(v);
    } else if (i < 4608) {   // cd2m [6 ic][64 lane][8 j]
      long jj = i - 1536;
      int ic = (int)(jj >> 9);
      int r = (int)(jj & 511);
      int lnn = r >> 3, j = r & 7;
      int n = lnn & 15, qd = lnn >> 4;
      int t = qd * 8 + j, ky = t / 6, kxp = t - ky * 6;
      float v = (t < 30 && kxp < 5)
          ? In<INF32>::ld(c2w, ((long)(n * 6 + ic) * 5 + ky) * 5 + kxp) : 0.f;
      cdh[1536 + jj] = f2h16(v);
    } else if (i < 4614) {   // cb1 (f32)
      ((float*)(cdw + 2304))[i - 4608] = In<INF32>::ld(c1b, i - 4608);
    } else if (i < 4630) {   // cb2 (f32)
      ((float*)(cdw + 2310))[i - 4614] = In<INF32>::ld(c2b, i - 4614);
    }
  }
}

// ---------------------------------------------------------------------------
// Conv kernel v7: MFMA implicit-GEMM, bank-decongruent copies (R7 geometry,
// byte-identical layout) + R8 VALU diet: all-int LDS indexing (no size_t /
// 64-bit addr math), incremental img/tau (no per-iter division), uint4
// global staging loads. Bank placement unchanged: sxs at +8 banks, sp1s at
// +16 banks.
// Out p2: [B][416] bf16, cols 400..415 zero.
// ---------------------------------------------------------------------------
#define CIMG 2
#define XSTR 34           // sx row stride (elems); 17 dw (odd)
#define PSTR 18           // sp1 row stride (elems); 9 dw (odd)
#define SXELEMS (CIMG * 3 * 32 * XSTR)   // 6528 u16 = 3264 dw == 0 (mod 32)
#define SPELEMS (CIMG * 6 * 14 * PSTR)   // 3024 u16 = 1512 dw == 8 (mod 32)
#define SXSHIFT (SXELEMS + 16)           // sxs base: dw 3272 == 8 (mod 32)
#define SPSHIFT (SPELEMS + 16)           // sp1s base: dw 1520 == 16 (mod 32)
template <bool INF32>
__global__ __launch_bounds__(256) void k_conv(
    const int* __restrict__ flag,
    const void* __restrict__ x,
    const uint32_t* __restrict__ cdw,
    u16* __restrict__ p2, int Btot) {
  if (*flag != (INF32 ? 1 : 0)) return;
  __shared__ __align__(16) u16 sxbuf[2 * SXELEMS + 16];
  __shared__ __align__(16) u16 sp1buf[2 * SPELEMS + 16];
  __shared__ u16 lut1[196];
  __shared__ u16 lut2[32];
  const u16* cdh = (const u16*)cdw;
  const float* cb1f = (const float*)(cdw + 2304);
  const float* cb2f = (const float*)(cdw + 2310);
  const int tid = threadIdx.x;
  const int wv = tid >> 6, ln = tid & 63;
  const int mrow = ln & 15, quad = ln >> 4;
  const long gimg0 = (long)blockIdx.x * CIMG;

  if (tid < 196) {
    int py = tid / 14, px = tid - py * 14;
    lut1[tid] = (u16)((2 * py) * XSTR + 2 * px);
  } else if (tid < 228) {
    int i = tid - 196;
    if (i < 25) {
      int py = i / 5, px = i - py * 5;
      lut2[i] = (u16)((2 * py) * PSTR + 2 * px);
    }
  }
  for (int r = tid; r < CIMG * 6 * 14; r += 256)
    *(uint32_t*)(sp1buf + SPSHIFT + r * PSTR + 12) = 0;

  // stage x -> f16 LDS (normal + shifted copies), uint4 global loads
  for (int i = tid; i < CIMG * 96; i += 256) {
    int img = (i >= 96) ? 1 : 0;          // CIMG == 2
    if (gimg0 + img >= Btot) continue;
    int rem = i - img * 96;
    long goff = (gimg0 + img) * 3072 + (long)rem * 32;
    uint32_t e[17];
    if (!INF32) {
      const uint4* src = (const uint4*)((const u16*)x + goff);
#pragma unroll
      for (int j = 0; j < 4; ++j) {
        uint4 d = src[j];
        e[4 * j + 0] = pk2h(__uint_as_float(d.x << 16), __uint_as_float(d.x & 0xffff0000u));
        e[4 * j + 1] = pk2h(__uint_as_float(d.y << 16), __uint_as_float(d.y & 0xffff0000u));
        e[4 * j + 2] = pk2h(__uint_as_float(d.z << 16), __uint_as_float(d.z & 0xffff0000u));
        e[4 * j + 3] = pk2h(__uint_as_float(d.w << 16), __uint_as_float(d.w & 0xffff0000u));
      }
    } else {
      const float4* src = (const float4*)((const float*)x + goff);
#pragma unroll
      for (int j = 0; j < 8; ++j) {
        float4 v = src[j];
        e[2 * j] = pk2h(v.x, v.y);
        e[2 * j + 1] = pk2h(v.z, v.w);
      }
    }
    e[16] = 0;
    const int b = i * XSTR;
    uint32_t* dn = (uint32_t*)(sxbuf + b);
    uint32_t* dsh = (uint32_t*)(sxbuf + SXSHIFT + b);
#pragma unroll
    for (int j = 0; j < 16; ++j) {
      dn[j] = e[j];
      dsh[j] = (e[j] >> 16) | (e[j + 1] << 16);
    }
  }

  h8v b1[3];
#pragma unroll
  for (int ic = 0; ic < 3; ++ic)
    b1[ic] = *(const h8v*)(cdh + ic * 512 + ln * 8);
  const float bias1 = (mrow < 6) ? cb1f[mrow] : 0.f;
  int toff1[4];
#pragma unroll
  for (int p = 0; p < 4; ++p) {
    int t = quad * 8 + 2 * p;
    if (t >= 30) t = 24;
    toff1[p] = (t / 6) * (XSTR - 6) + t;
  }
  const int qA = mrow >> 2, dyA = (mrow >> 1) & 1, dxA = mrow & 1;

  __syncthreads();

  // conv1 + relu + pool -> sp1; int indexing, incremental img/tau
  {
    const int c1off = dxA ? SXSHIFT : 0;
    int img = 0, tau = wv;
    for (int tg = wv; tg < CIMG * 49; tg += 4) {
      int pqA = tau * 4 + qA;
      int rb0 = c1off + img * (3 * 32 * XSTR) + lut1[pqA] + dyA * XSTR;
      f4v acc = {0.f, 0.f, 0.f, 0.f};
#pragma unroll
      for (int ic = 0; ic < 3; ++ic) {
        int rb = rb0 + ic * (32 * XSTR);
        union { uint32_t w[4]; h8v v; } au;
#pragma unroll
        for (int p = 0; p < 4; ++p)
          au.w[p] = *(const uint32_t*)(sxbuf + rb + toff1[p]);
        acc = __builtin_amdgcn_mfma_f32_16x16x32_f16(au.v, b1[ic], acc, 0, 0, 0);
      }
      float v = fmaxf(fmaxf(acc[0], acc[1]), fmaxf(acc[2], acc[3])) + bias1;
      v = fmaxf(v, 0.f);
      if (mrow < 6) {
        int pqC = tau * 4 + quad;
        int py = (pqC * 4682) >> 16, px = pqC - py * 14;
        int rbase = ((img * 6 + mrow) * 14 + py) * PSTR;
        u16 hv = f2h16(v);
        sp1buf[rbase + px] = hv;
        sp1buf[SPSHIFT + rbase + (px ? px - 1 : PSTR - 1)] = hv;
      }
      tau += 4;
      if (tau >= 49) { tau -= 49; ++img; }
    }
  }

  h8v b2[6];
#pragma unroll
  for (int ic = 0; ic < 6; ++ic)
    b2[ic] = *(const h8v*)(cdh + 1536 + ic * 512 + ln * 8);
  const float bias2 = cb2f[mrow];
  int toff2[4];
#pragma unroll
  for (int p = 0; p < 4; ++p) {
    int t = quad * 8 + 2 * p;
    if (t >= 30) t = 24;
    toff2[p] = (t / 6) * (PSTR - 6) + t;
  }

  __syncthreads();

  // conv2 + relu + pool -> p2
  {
    const int NP2 = CIMG * 25;
    const int c2off = dxA ? SPSHIFT : 0;
    for (int t2 = wv; t2 * 4 < NP2; t2 += 4) {
      int PA = t2 * 4 + qA;
      if (PA >= NP2) PA = NP2 - 1;
      int img2 = (PA >= 25) ? 1 : 0;      // CIMG == 2
      int pq = PA - img2 * 25;
      int rb0 = c2off + img2 * (6 * 14 * PSTR) + lut2[pq] + dyA * PSTR;
      f4v acc = {0.f, 0.f, 0.f, 0.f};
#pragma unroll
      for (int ic = 0; ic < 6; ++ic) {
        int rb = rb0 + ic * (14 * PSTR);
        union { uint32_t w[4]; h8v v; } au;
#pragma unroll
        for (int p = 0; p < 4; ++p)
          au.w[p] = *(const uint32_t*)(sp1buf + rb + toff2[p]);
        acc = __builtin_amdgcn_mfma_f32_16x16x32_f16(au.v, b2[ic], acc, 0, 0, 0);
      }
      float v = fmaxf(fmaxf(acc[0], acc[1]), fmaxf(acc[2], acc[3])) + bias2;
      v = fmaxf(v, 0.f);
      int PC = t2 * 4 + quad;
      if (PC < NP2) {
        int imgc = (PC >= 25) ? 1 : 0;
        int pqc = PC - imgc * 25;
        if (gimg0 + imgc < Btot)
          p2[(gimg0 + imgc) * 416 + mrow * 25 + pqc] = f2bu(v);
      }
    }
  }

  for (int i = tid; i < CIMG * 16; i += 256) {
    int img = i / 16;
    if (gimg0 + img < Btot) p2[(gimg0 + img) * 416 + 400 + (i & 15)] = 0;
  }
}

// ---------------------------------------------------------------------------
// fcA: fc1 -> fc2 -> gate. 64 tokens/block (unchanged).
// ---------------------------------------------------------------------------
template <bool INF32>
__global__ __launch_bounds__(256) void k_fcA(
    const int* __restrict__ flag,
    const u16* __restrict__ p2,
    const u16* __restrict__ fc1t, const u16* __restrict__ fc2t,
    const void* __restrict__ fc1b, const void* __restrict__ fc2b,
    const void* __restrict__ gw,
    u16* __restrict__ a2buf, float* __restrict__ scbuf) {
  if (*flag != (INF32 ? 1 : 0)) return;
  __shared__ __align__(16) char smem[62976];
  u16* a2s = (u16*)smem;                    // [64][104]
  u16* hs = (u16*)(smem + 13312);           // [64][136]
  u16* wbuf = (u16*)(smem + 31232);
  u16* xs = (u16*)(smem + 57856);           // [64][40]

  const int tid = threadIdx.x;
  const int wv = tid >> 6, ln = tid & 63;
  const int m = ln & 15, quad = ln >> 4;
  const long t0 = (long)blockIdx.x * 64;
  const int row0 = wv * 16 + quad * 4;

  for (int i = tid; i < 30720 / 4; i += 256) ((uint32_t*)smem)[i] = 0;

  // fc1
  f4v acc1[8];
#pragma unroll
  for (int i = 0; i < 8; ++i) acc1[i] = (f4v){0.f, 0.f, 0.f, 0.f};
  for (int s = 0; s < 13; ++s) {
    {
      int r = tid >> 2, c0 = (tid & 3) * 8;
      *(uint4*)(xs + r * 40 + c0) =
          *(const uint4*)(p2 + (t0 + r) * 416 + s * 32 + c0);
      int n = tid >> 1, cw = (tid & 1) * 16;
      *(uint4*)(wbuf + n * 40 + cw) = *(const uint4*)(fc1t + (long)n * 416 + s * 32 + cw);
      *(uint4*)(wbuf + n * 40 + cw + 8) =
          *(const uint4*)(fc1t + (long)n * 416 + s * 32 + cw + 8);
    }
    __syncthreads();
    s8v a = *(const s8v*)(xs + (wv * 16 + m) * 40 + quad * 8);
#pragma unroll
    for (int nt = 0; nt < 8; ++nt) {
      s8v b = *(const s8v*)(wbuf + (nt * 16 + m) * 40 + quad * 8);
      acc1[nt] = __builtin_amdgcn_mfma_f32_16x16x32_bf16(a, b, acc1[nt], 0, 0, 0);
    }
    __syncthreads();
  }
#pragma unroll
  for (int nt = 0; nt < 8; ++nt) {
    int n = nt * 16 + m;
    if (n < 120) {
      float bv = In<INF32>::ld(fc1b, n);
#pragma unroll
      for (int r = 0; r < 4; ++r)
        hs[(row0 + r) * 136 + n] = f2bu(fmaxf(acc1[nt][r] + bv, 0.f));
    }
  }
  __syncthreads();

  // fc2
  for (int i = tid; i < 1536; i += 256) {
    int n = i >> 4, c0 = (i & 15) * 8;
    *(uint4*)(wbuf + n * 136 + c0) = *(const uint4*)(fc2t + n * 128 + c0);
  }
  __syncthreads();
  f4v acc2[6];
#pragma unroll
  for (int i = 0; i < 6; ++i) acc2[i] = (f4v){0.f, 0.f, 0.f, 0.f};
  for (int s = 0; s < 4; ++s) {
    s8v a = *(const s8v*)(hs + (wv * 16 + m) * 136 + s * 32 + quad * 8);
#pragma unroll
    for (int nt = 0; nt < 6; ++nt) {
      s8v b = *(const s8v*)(wbuf + (nt * 16 + m) * 136 + s * 32 + quad * 8);
      acc2[nt] = __builtin_amdgcn_mfma_f32_16x16x32_bf16(a, b, acc2[nt], 0, 0, 0);
    }
  }
  __syncthreads();
#pragma unroll
  for (int nt = 0; nt < 6; ++nt) {
    int n = nt * 16 + m;
    if (n < 84) {
      float bv = In<INF32>::ld(fc2b, n);
#pragma unroll
      for (int r = 0; r < 4; ++r)
        a2s[(row0 + r) * 104 + n] = f2bu(fmaxf(acc2[nt][r] + bv, 0.f));
    }
  }
  __syncthreads();

  // gate + writeback
  if (tid < 64) {
    const u16* xr = a2s + tid * 104;
    float l0 = 0.f, l1 = 0.f;
    for (int k = 0; k < 84; ++k) {
      float xv = bu2f(xr[k]);
      l0 = fmaf(xv, In<INF32>::ld(gw, 2 * k), l0);
      l1 = fmaf(xv, In<INF32>::ld(gw, 2 * k + 1), l1);
    }
    float mx = fmaxf(l0, l1);
    float e0 = __expf(l0 - mx), e1 = __expf(l1 - mx);
    float inv = 1.f / (e0 + e1);
    *(float2*)(scbuf + (t0 + tid) * 2) = make_float2(e0 * inv, e1 * inv);
  }
  for (int i = tid; i < 832; i += 256) {  // 64 rows x 13 uint4
    int r = i / 13, c0 = (i - r * 13) * 8;
    *(uint4*)(a2buf + (t0 + r) * 104 + c0) = *(const uint4*)(a2s + r * 104 + c0);
  }
}

// ---------------------------------------------------------------------------
// exp: one expert per block (grid = [B/64, 2]) -> ybuf [2][B][96] f32.
// (R5-proven version, unchanged.)
// ---------------------------------------------------------------------------
template <bool INF32>
__global__ __launch_bounds__(256) void k_exp(
    const int* __restrict__ flag,
    const u16* __restrict__ a2buf, const float* __restrict__ scbuf,
    const u16* __restrict__ w1t, const u16* __restrict__ w2t,
    const void* __restrict__ eb1, const void* __restrict__ eb2,
    float* __restrict__ ybuf, int Btok) {
  if (*flag != (INF32 ? 1 : 0)) return;
  __shared__ __align__(16) char smem[57856];
  u16* a2s = (u16*)smem;                    // [64][104]
  u16* hs = (u16*)(smem + 13312);           // [64][136]
  u16* wbuf = (u16*)(smem + 30720);         // 26,624 B
  float* scs = (float*)(smem + 57344);      // [64]

  const int tid = threadIdx.x;
  const int wv = tid >> 6, ln = tid & 63;
  const int m = ln & 15, quad = ln >> 4;
  const int e = blockIdx.y;
  const long t0 = (long)blockIdx.x * 64;
  const int row0 = wv * 16 + quad * 4;
  const u16* w1te = w1t + (long)e * 196608;
  const u16* w2te = w2t + (long)e * 196608;

  for (int i = tid; i < 832; i += 256) {
    int r = i / 13, c0 = (i - r * 13) * 8;
    *(uint4*)(a2s + r * 104 + c0) = *(const uint4*)(a2buf + (t0 + r) * 104 + c0);
  }
  if (tid < 64) scs[tid] = scbuf[(t0 + tid) * 2 + e];
  __syncthreads();

  f4v acce[6];
#pragma unroll
  for (int i = 0; i < 6; ++i) acce[i] = (f4v){0.f, 0.f, 0.f, 0.f};
  for (int c = 0; c < 16; ++c) {
    const int n0 = c * 128;
    if (c) __syncthreads();
    for (int i = tid; i < 1536; i += 256) {  // wbuf[128][104] <- w1t chunk
      int nl = i / 12, c0 = (i - nl * 12) * 8;
      *(uint4*)(wbuf + nl * 104 + c0) =
          *(const uint4*)(w1te + (long)(n0 + nl) * 96 + c0);
    }
    __syncthreads();
    f4v acch[8];
#pragma unroll
    for (int i = 0; i < 8; ++i) acch[i] = (f4v){0.f, 0.f, 0.f, 0.f};
    for (int s = 0; s < 3; ++s) {
      s8v a = *(const s8v*)(a2s + (wv * 16 + m) * 104 + s * 32 + quad * 8);
#pragma unroll
      for (int nt = 0; nt < 8; ++nt) {
        s8v b = *(const s8v*)(wbuf + (nt * 16 + m) * 104 + s * 32 + quad * 8);
        acch[nt] = __builtin_amdgcn_mfma_f32_16x16x32_bf16(a, b, acch[nt], 0, 0, 0);
      }
    }
#pragma unroll
    for (int nt = 0; nt < 8; ++nt) {
      float bv = In<INF32>::ld(eb1, (long)e * 2048 + n0 + nt * 16 + m);
#pragma unroll
      for (int r = 0; r < 4; ++r)
        hs[(row0 + r) * 136 + nt * 16 + m] = f2bu(fmaxf(acch[nt][r] + bv, 0.f));
    }
    __syncthreads();
    for (int i = tid; i < 1536; i += 256) {  // wbuf[96][136] <- w2t slice
      int n = i >> 4, c0 = (i & 15) * 8;
      *(uint4*)(wbuf + n * 136 + c0) =
          *(const uint4*)(w2te + (long)n * 2048 + n0 + c0);
    }
    __syncthreads();
    for (int s = 0; s < 4; ++s) {
      s8v a = *(const s8v*)(hs + (wv * 16 + m) * 136 + s * 32 + quad * 8);
#pragma unroll
      for (int nt = 0; nt < 6; ++nt) {
        s8v b = *(const s8v*)(wbuf + (nt * 16 + m) * 136 + s * 32 + quad * 8);
        acce[nt] = __builtin_amdgcn_mfma_f32_16x16x32_bf16(a, b, acce[nt], 0, 0, 0);
      }
    }
  }

  // y_e = sc * (acce + b2) -> ybuf
#pragma unroll
  for (int nt = 0; nt < 6; ++nt) {
    int d = nt * 16 + m;
    float bv = (d < 84) ? In<INF32>::ld(eb2, (long)e * 84 + d) : 0.f;
#pragma unroll
    for (int r = 0; r < 4; ++r) {
      float sc = scs[row0 + r];
      ybuf[((size_t)e * Btok + t0 + row0 + r) * 96 + d] = sc * (acce[nt][r] + bv);
    }
  }
}

// ---------------------------------------------------------------------------
// fc3 v2: out = (y0 + y1) @ w3 + b3. One token per thread, float4 reads
// (R8: removes the 10x redundant row re-reads of the task-per-output form).
// grid = B/256.
// ---------------------------------------------------------------------------
template <bool INF32>
__global__ __launch_bounds__(256) void k_fc3(
    const int* __restrict__ flag,
    const float* __restrict__ ybuf,
    const void* __restrict__ w3, const void* __restrict__ b3,
    void* __restrict__ out, int Btok) {
  if (*flag != (INF32 ? 1 : 0)) return;
  __shared__ float sw3[840];
  __shared__ float sb3[10];
  const int tid = threadIdx.x;
  for (int i = tid; i < 840; i += 256) sw3[i] = In<INF32>::ld(w3, i);
  if (tid < 10) sb3[tid] = In<INF32>::ld(b3, tid);
  __syncthreads();
  const long tk = (long)blockIdx.x * 256 + tid;
  const float4* y0r = (const float4*)(ybuf + tk * 96);
  const float4* y1r = (const float4*)(ybuf + ((size_t)Btok + tk) * 96);
  float o[10];
#pragma unroll
  for (int c = 0; c < 10; ++c) o[c] = sb3[c];
#pragma unroll
  for (int d4 = 0; d4 < 21; ++d4) {
    float4 a = y0r[d4], b = y1r[d4];
    float s0 = a.x + b.x, s1 = a.y + b.y, s2 = a.z + b.z, s3 = a.w + b.w;
    const float* w = sw3 + d4 * 40;
#pragma unroll
    for (int c = 0; c < 10; ++c)
      o[c] = fmaf(s0, w[c],
             fmaf(s1, w[10 + c],
             fmaf(s2, w[20 + c],
             fmaf(s3, w[30 + c], o[c]))));
  }
  long oi = tk * 10;
  if (INF32) {
#pragma unroll
    for (int c = 0; c < 10; ++c) ((float*)out)[oi + c] = o[c];
  } else {
#pragma unroll
    for (int c = 0; c < 10; ++c) ((u16*)out)[oi + c] = f2bu(o[c]);
  }
}

// ---------------------------------------------------------------------------
extern "C" void kernel_launch(void* const* d_in, const int* in_sizes, int n_in,
                              void* d_out, int out_size, void* d_ws, size_t ws_size,
                              hipStream_t stream) {
  const int B = in_sizes[0] / 3072;  // 16384
  char* wsb = (char*)d_ws;
  int* flag = (int*)wsb;
  u16* p2 = (u16*)(wsb + 64);                    // [B][416] bf16
  u16* fc1t = p2 + (size_t)B * 416;              // 53,248 elems
  u16* fc2t = fc1t + 53248;                      // 12,288
  u16* w1t = fc2t + 12288;                       // 393,216
  u16* w2t = w1t + 393216;                       // 393,216
  uint32_t* cdw = (uint32_t*)(w2t + 393216);     // 2,326 dwords
  u16* a2buf = (u16*)(cdw + 2326);               // [B][104] bf16
  float* scbuf = (float*)(a2buf + (size_t)B * 104);  // [B][2] f32
  float* ybuf = scbuf + (size_t)B * 2;           // [2][B][96] f32

  k_detect<<<1, 64, 0, stream>>>((const u16*)d_in[0], flag);

  // 856,598 work items -> 3347 blocks (tail 22 items are the conv biases).
  k_trans<false><<<3347, 256, 0, stream>>>(flag, d_in[5], d_in[7], d_in[10],
                                           d_in[12], d_in[1], d_in[2], d_in[3],
                                           d_in[4], fc1t, fc2t, w1t, w2t, cdw);
  k_trans<true><<<3347, 256, 0, stream>>>(flag, d_in[5], d_in[7], d_in[10],
                                          d_in[12], d_in[1], d_in[2], d_in[3],
                                          d_in[4], fc1t, fc2t, w1t, w2t, cdw);

  const int convGrid = (B + CIMG - 1) / CIMG;
  k_conv<false><<<convGrid, 256, 0, stream>>>(flag, d_in[0], cdw, p2, B);
  k_conv<true><<<convGrid, 256, 0, stream>>>(flag, d_in[0], cdw, p2, B);

  k_fcA<false><<<B / 64, 256, 0, stream>>>(flag, p2, fc1t, fc2t, d_in[6],
                                           d_in[8], d_in[9], a2buf, scbuf);
  k_fcA<true><<<B / 64, 256, 0, stream>>>(flag, p2, fc1t, fc2t, d_in[6],
                                          d_in[8], d_in[9], a2buf, scbuf);

  dim3 eg(B / 64, 2);
  k_exp<false><<<eg, 256, 0, stream>>>(flag, a2buf, scbuf, w1t, w2t, d_in[11],
                                       d_in[13], ybuf, B);
  k_exp<true><<<eg, 256, 0, stream>>>(flag, a2buf, scbuf, w1t, w2t, d_in[11],
                                      d_in[13], ybuf, B);

  k_fc3<false><<<B / 256, 256, 0, stream>>>(flag, ybuf, d_in[14], d_in[15],
                                            d_out, B);
  k_fc3<true><<<B / 256, 256, 0, stream>>>(flag, ybuf, d_in[14], d_in[15],
                                           d_out, B);
}